// Round 10
// baseline (68.529 us; speedup 1.0000x reference)
//
#include <hip/hip_runtime.h>
#include <stdint.h>

#define NB    64       // batch
#define KMAX  16
#define VV    32000    // vocab
#define DVV   10
#define HH    4096
#define NROWS (NB*KMAX)
#define EPSF  1e-8f
#define NQ    8000     // float4 groups per row (4*8000 = 32000)

typedef float floatx4 __attribute__((ext_vector_type(4)));

// ---------------- Threefry-2x32 (exact JAX reference implementation) ----------------
__device__ __forceinline__ uint32_t rotl32(uint32_t v, int r) { return (v << r) | (v >> (32 - r)); }

__device__ __forceinline__ void tf2x32(uint32_t k0, uint32_t k1, uint32_t c0, uint32_t c1,
                                       uint32_t& o0, uint32_t& o1) {
    uint32_t ks2 = k0 ^ k1 ^ 0x1BD11BDAu;
    uint32_t x0 = c0 + k0, x1 = c1 + k1;
    const int RA[4] = {13, 15, 26, 6};
    const int RB[4] = {17, 29, 16, 24};
#pragma unroll
    for (int i = 0; i < 4; ++i) { x0 += x1; x1 = rotl32(x1, RA[i]); x1 ^= x0; }
    x0 += k1; x1 += ks2 + 1u;
#pragma unroll
    for (int i = 0; i < 4; ++i) { x0 += x1; x1 = rotl32(x1, RB[i]); x1 ^= x0; }
    x0 += ks2; x1 += k0 + 2u;
#pragma unroll
    for (int i = 0; i < 4; ++i) { x0 += x1; x1 = rotl32(x1, RA[i]); x1 ^= x0; }
    x0 += k0; x1 += k1 + 3u;
#pragma unroll
    for (int i = 0; i < 4; ++i) { x0 += x1; x1 = rotl32(x1, RB[i]); x1 ^= x0; }
    x0 += k1; x1 += ks2 + 4u;
#pragma unroll
    for (int i = 0; i < 4; ++i) { x0 += x1; x1 = rotl32(x1, RA[i]); x1 ^= x0; }
    x0 += ks2; x1 += k0 + 5u;
    o0 = x0; o1 = x1;
}

__device__ __forceinline__ float bits_to_u01(uint32_t bits) {
    uint32_t fb = (bits >> 9) | 0x3F800000u;
    return __uint_as_float(fb) - 1.0f;
}

__device__ __forceinline__ void nt_store4(float* p, float a, float b, float c, float d) {
    floatx4 v = {a, b, c, d};
    __builtin_nontemporal_store(v, (floatx4*)p);
}

// ------------- mega: blocks 0..63 rowred(+ticket finalize); 64.. row blocks -------------
// Row blocks derive their descriptor in-block (first 16 lanes: lane t = batch
// slot t; stable rank via 16-lane shfl; inverse-perm match r==s). dst row base
// ≡ 3 mod 4 floats: NT stores 16B-aligned at dst+4q+1, loads dword-aligned
// unaligned float4 of the same span. Warp rows cache the row in r[8] float4
// regs -> one global read, one write. Edges by threads 0/1.
__global__ __launch_bounds__(1024) void mega_kernel(const float* __restrict__ p_z,
                                                    const int* __restrict__ k_vals,
                                                    const float* __restrict__ dlr,
                                                    const float* __restrict__ dlc,
                                                    const float* __restrict__ hr,
                                                    const float* __restrict__ hc,
                                                    float* __restrict__ cosb,
                                                    float* __restrict__ depb,
                                                    int* __restrict__ counter,
                                                    float* __restrict__ out) {
    const int tid = threadIdx.x;

    if (blockIdx.x < NB) {
        // ---------------- rowred: batch b, 1024 threads = HH/4 float4 ----------------
        const int b = blockIdx.x;
        const float4* r4 = (const float4*)(hr + (size_t)b * HH);
        const float4* c4 = (const float4*)(hc + (size_t)b * HH);
        float4 rr = r4[tid], cc = c4[tid];
        float srr = rr.x * rr.x + rr.y * rr.y + rr.z * rr.z + rr.w * rr.w;
        float scc = cc.x * cc.x + cc.y * cc.y + cc.z * cc.z + cc.w * cc.w;
        float sxc = rr.x * cc.x + rr.y * cc.y + rr.z * cc.z + rr.w * cc.w;
        float dx = rr.x - cc.x, dy = rr.y - cc.y, dz = rr.z - cc.z, dw = rr.w - cc.w;
        float sdd = dx * dx + dy * dy + dz * dz + dw * dw;
#pragma unroll
        for (int o = 32; o; o >>= 1) {
            srr += __shfl_down(srr, o, 64);
            scc += __shfl_down(scc, o, 64);
            sxc += __shfl_down(sxc, o, 64);
            sdd += __shfl_down(sdd, o, 64);
        }
        __shared__ float red[16][4];
        __shared__ int s_ticket;
        const int w = tid >> 6;
        if ((tid & 63) == 0) { red[w][0] = srr; red[w][1] = scc; red[w][2] = sxc; red[w][3] = sdd; }
        __syncthreads();
        if (tid == 0) {
            float t0 = 0.f, t1 = 0.f, t2 = 0.f, t3 = 0.f;
            for (int i = 0; i < 16; ++i) { t0 += red[i][0]; t1 += red[i][1]; t2 += red[i][2]; t3 += red[i][3]; }
            float nr = fmaxf(sqrtf(t0), 1e-12f);
            float nc = fmaxf(sqrtf(t1), 1e-12f);
            cosb[b] = t2 / (nr * nc);
            depb[b] = sqrtf(t3);
            __threadfence();                 // publish before ticket
            s_ticket = atomicAdd(counter, 1);
        }
        __syncthreads();
        if (s_ticket != NB - 1) return;      // not the last rowred block
        __threadfence();                     // acquire all cosb/depb

        // ---------------- finalize (first wave; deterministic) ----------------
        if (tid < 64) {
            const int bb = tid;
            float lr[DVV], lc[DVV];
            float mr = -1e30f, mc = -1e30f;
#pragma unroll
            for (int v = 0; v < DVV; ++v) {
                lr[v] = dlr[bb * DVV + v]; lc[v] = dlc[bb * DVV + v];
                mr = fmaxf(mr, lr[v]); mc = fmaxf(mc, lc[v]);
            }
            float sr = 0.f, sc = 0.f;
#pragma unroll
            for (int v = 0; v < DVV; ++v) {
                lr[v] = expf(lr[v] - mr); sr += lr[v];
                lc[v] = expf(lc[v] - mc); sc += lc[v];
            }
            float js = 0.f;
#pragma unroll
            for (int v = 0; v < DVV; ++v) {
                float p = fmaxf(lr[v] / sr, EPSF);
                float q = fmaxf(lc[v] / sc, EPSF);
                float m = 0.5f * (p + q);
                float lm = logf(m);
                js += 0.5f * (p * (logf(p) - lm) + q * (logf(q) - lm));
            }
            float cs = cosb[bb], dpv = depb[bb];
#pragma unroll
            for (int o = 32; o; o >>= 1) {
                js += __shfl_down(js, o, 64);
                cs += __shfl_down(cs, o, 64);
                dpv += __shfl_down(dpv, o, 64);
            }
            if (tid == 0) {
                out[0] = logf(2.0f) - js * (1.0f / 64.0f);
                out[1] = cs * (1.0f / 64.0f) - 1.0f;
                out[2] = dpv * (1.0f / 64.0f);
            }
        }
        return;
    }

    // ---------------- row block ----------------
    const int row = blockIdx.x - NB;
    const int b = row >> 4, s = row & 15;
    float* dst = out + 3 + (size_t)row * VV;

    __shared__ int   s_src;
    __shared__ float s_itau;

    if (tid < 16) {
        const int t = tid;
        uint32_t a0, b0_, a1, b1_, a2, b2_, y0, y1;
        tf2x32(0u, 0u, 0u, 3u, a0, b0_);
        tf2x32(0u, 0u, 1u, 4u, a1, b1_);
        tf2x32(0u, 0u, 2u, 5u, a2, b2_);
        const uint32_t kdec0 = a0, kdec1 = a1;
        const uint32_t kperm0 = a2, kperm1 = b0_;
        const uint32_t ktau0 = b1_, ktau1 = b2_;

        const int k = k_vals[b];

        uint32_t bits;
        if (b < 32) { tf2x32(kdec0, kdec1, (uint32_t)b, (uint32_t)(b + 32), y0, y1); bits = y0; }
        else        { tf2x32(kdec0, kdec1, (uint32_t)(b - 32), (uint32_t)b, y0, y1); bits = y1; }
        const float u_dec = bits_to_u01(bits);
        const bool dp = (k > 1) && (u_dec < ((k >= 2) ? 0.5f : 0.0f));

        const int j = (b << 4) + t;
        uint32_t pb;
        if (j < 512) { tf2x32(kperm0, kperm1, (uint32_t)j, (uint32_t)(j + 512), y0, y1); pb = y0; }
        else         { tf2x32(kperm0, kperm1, (uint32_t)(j - 512), (uint32_t)j, y0, y1); pb = y1; }
        const float up = bits_to_u01(pb);

        const float INF = __int_as_float(0x7F800000);
        const float keyt = (t < k) ? up : INF;
        int r = 0;
#pragma unroll
        for (int tt = 0; tt < KMAX; ++tt) {
            float kt = __shfl(keyt, tt, 64);
            r += (kt < keyt) || (kt == keyt && tt < t);
        }

        if (s >= k)  { if (t == 0) { s_src = s; s_itau = 0.f; } }    // inactive: self-copy
        else if (dp) { if (r == s) { s_src = t; s_itau = 0.f; } }    // permuted: inverse perm
        else if (t == 0) {                                            // warp: tau for (b,s)
            const int js = (b << 4) + s;
            uint32_t tb;
            if (js < 512) { tf2x32(ktau0, ktau1, (uint32_t)js, (uint32_t)(js + 512), y0, y1); tb = y0; }
            else          { tf2x32(ktau0, ktau1, (uint32_t)(js - 512), (uint32_t)js, y0, y1); tb = y1; }
            const float tau = fmaxf(0.7f, bits_to_u01(tb) * 0.9f + 0.7f);
            s_src = -1; s_itau = 1.0f / tau;
        }
    }
    __syncthreads();

    const int src = s_src;

    if (src >= 0) {  // copy (self or permuted slot): one read, one NT write
        const float* sp = p_z + ((size_t)((b << 4) + src)) * VV;
#pragma unroll
        for (int i = 0; i < 8; ++i) {
            const int q = tid + (i << 10);
            if (q < NQ - 1) {
                float4 v = *(const float4*)(sp + (q << 2) + 1);
                nt_store4(dst + (q << 2) + 1, v.x, v.y, v.z, v.w);
            }
        }
        if (tid == 0) dst[0] = sp[0];
        if (tid == 1) {
            dst[VV - 3] = sp[VV - 3];
            dst[VV - 2] = sp[VV - 2];
            dst[VV - 1] = sp[VV - 1];
        }
        return;
    }

    // temperature warp: p^(1/tau) / sum(p^(1/tau)); row cached in registers.
    const float it = s_itau;
    const float* sp = p_z + (size_t)row * VV;
    float4 r[8];
    float e0 = 0.f, t0 = 0.f, t1 = 0.f, t2 = 0.f;
    float lsum = 0.f;
#pragma unroll
    for (int i = 0; i < 8; ++i) {
        const int q = tid + (i << 10);
        if (q < NQ - 1) {
            float4 v = *(const float4*)(sp + (q << 2) + 1);
            v.x = exp2f(__log2f(fmaxf(v.x, EPSF)) * it);
            v.y = exp2f(__log2f(fmaxf(v.y, EPSF)) * it);
            v.z = exp2f(__log2f(fmaxf(v.z, EPSF)) * it);
            v.w = exp2f(__log2f(fmaxf(v.w, EPSF)) * it);
            r[i] = v;
            lsum += v.x + v.y + v.z + v.w;
        } else {
            r[i] = make_float4(0.f, 0.f, 0.f, 0.f);
        }
    }
    if (tid == 0) { e0 = exp2f(__log2f(fmaxf(sp[0], EPSF)) * it); lsum += e0; }
    if (tid == 1) {
        t0 = exp2f(__log2f(fmaxf(sp[VV - 3], EPSF)) * it);
        t1 = exp2f(__log2f(fmaxf(sp[VV - 2], EPSF)) * it);
        t2 = exp2f(__log2f(fmaxf(sp[VV - 1], EPSF)) * it);
        lsum += t0 + t1 + t2;
    }
    // block reduce (16 waves)
    __shared__ float red1[16];
    float t = lsum;
#pragma unroll
    for (int o = 32; o; o >>= 1) t += __shfl_down(t, o, 64);
    if ((tid & 63) == 0) red1[tid >> 6] = t;
    __syncthreads();
    if (tid < 64) {
        float u = (tid < 16) ? red1[tid] : 0.0f;
#pragma unroll
        for (int o = 8; o; o >>= 1) u += __shfl_down(u, o, 64);
        if (tid == 0) red1[0] = u;
    }
    __syncthreads();
    const float scale = 1.0f / red1[0];

#pragma unroll
    for (int i = 0; i < 8; ++i) {
        const int q = tid + (i << 10);
        if (q < NQ - 1) {
            nt_store4(dst + (q << 2) + 1,
                      r[i].x * scale, r[i].y * scale, r[i].z * scale, r[i].w * scale);
        }
    }
    if (tid == 0) dst[0] = e0 * scale;
    if (tid == 1) {
        dst[VV - 3] = t0 * scale;
        dst[VV - 2] = t1 * scale;
        dst[VV - 1] = t2 * scale;
    }
}

extern "C" void kernel_launch(void* const* d_in, const int* in_sizes, int n_in,
                              void* d_out, int out_size, void* d_ws, size_t ws_size,
                              hipStream_t stream) {
    const float* p_z = (const float*)d_in[0];
    const float* dlr = (const float*)d_in[1];
    const float* dlc = (const float*)d_in[2];
    const float* hr  = (const float*)d_in[3];
    const float* hc  = (const float*)d_in[4];
    const int*   kv  = (const int*)d_in[5];
    float* out = (float*)d_out;

    float* cosb    = (float*)d_ws;
    float* depb    = cosb + NB;
    int*   counter = (int*)(depb + NB);

    hipMemsetAsync(counter, 0, sizeof(int), stream);
    mega_kernel<<<NB + NROWS, 1024, 0, stream>>>(p_z, kv, dlr, dlc, hr, hc,
                                                 cosb, depb, counter, out);
}

// Round 11
// 55.845 us; speedup vs baseline: 1.2271x; 1.2271x over previous
//
#include <hip/hip_runtime.h>
#include <stdint.h>

#define NB    64       // batch
#define KMAX  16
#define VV    32000    // vocab
#define DVV   10
#define HH    4096
#define NROWS (NB*KMAX)
#define EPSF  1e-8f
#define NQ    8000     // float4 groups per row (4*8000 = 32000)

typedef float floatx4 __attribute__((ext_vector_type(4)));

// ---------------- Threefry-2x32 (exact JAX reference implementation) ----------------
__device__ __forceinline__ uint32_t rotl32(uint32_t v, int r) { return (v << r) | (v >> (32 - r)); }

__device__ __forceinline__ void tf2x32(uint32_t k0, uint32_t k1, uint32_t c0, uint32_t c1,
                                       uint32_t& o0, uint32_t& o1) {
    uint32_t ks2 = k0 ^ k1 ^ 0x1BD11BDAu;
    uint32_t x0 = c0 + k0, x1 = c1 + k1;
    const int RA[4] = {13, 15, 26, 6};
    const int RB[4] = {17, 29, 16, 24};
#pragma unroll
    for (int i = 0; i < 4; ++i) { x0 += x1; x1 = rotl32(x1, RA[i]); x1 ^= x0; }
    x0 += k1; x1 += ks2 + 1u;
#pragma unroll
    for (int i = 0; i < 4; ++i) { x0 += x1; x1 = rotl32(x1, RB[i]); x1 ^= x0; }
    x0 += ks2; x1 += k0 + 2u;
#pragma unroll
    for (int i = 0; i < 4; ++i) { x0 += x1; x1 = rotl32(x1, RA[i]); x1 ^= x0; }
    x0 += k0; x1 += k1 + 3u;
#pragma unroll
    for (int i = 0; i < 4; ++i) { x0 += x1; x1 = rotl32(x1, RB[i]); x1 ^= x0; }
    x0 += k1; x1 += ks2 + 4u;
#pragma unroll
    for (int i = 0; i < 4; ++i) { x0 += x1; x1 = rotl32(x1, RA[i]); x1 ^= x0; }
    x0 += ks2; x1 += k0 + 5u;
    o0 = x0; o1 = x1;
}

__device__ __forceinline__ float bits_to_u01(uint32_t bits) {
    uint32_t fb = (bits >> 9) | 0x3F800000u;
    return __uint_as_float(fb) - 1.0f;
}

__device__ __forceinline__ void nt_store4(float* p, float a, float b, float c, float d) {
    floatx4 v = {a, b, c, d};
    __builtin_nontemporal_store(v, (floatx4*)p);
}

// ------------- main: build p_cf_z (one block per row; LDS does the +3 shift) -------------
// Pass 1: ALIGNED float4 global loads -> LDS (warp rows apply pow here, once).
// Barrier (+ sum reduce for warp rows). Pass 2: LDS read at +1-float shift ->
// ALIGNED 16B NT global stores at dst+4q+1 (dst base ≡ 3 mod 4 floats). Both
// global streams fully aligned; LDS absorbs the misalignment.
__global__ __launch_bounds__(1024) void cf_main_kernel(const float* __restrict__ p_z,
                                                       const int* __restrict__ k_vals,
                                                       float* __restrict__ out) {
    const int row = blockIdx.x;
    const int b = row >> 4, s = row & 15;
    const int tid = threadIdx.x;
    float* dst = out + 3 + (size_t)row * VV;

    __shared__ float buf[VV];          // 128 KB row stage
    __shared__ float red1[16];
    __shared__ int   s_src;
    __shared__ float s_itau;

    // ---- in-block setup (first 16 lanes; R7-proven) ----
    if (tid < 16) {
        const int t = tid;
        uint32_t a0, b0_, a1, b1_, a2, b2_, y0, y1;
        tf2x32(0u, 0u, 0u, 3u, a0, b0_);
        tf2x32(0u, 0u, 1u, 4u, a1, b1_);
        tf2x32(0u, 0u, 2u, 5u, a2, b2_);
        const uint32_t kdec0 = a0, kdec1 = a1;
        const uint32_t kperm0 = a2, kperm1 = b0_;
        const uint32_t ktau0 = b1_, ktau1 = b2_;

        const int k = k_vals[b];

        uint32_t bits;
        if (b < 32) { tf2x32(kdec0, kdec1, (uint32_t)b, (uint32_t)(b + 32), y0, y1); bits = y0; }
        else        { tf2x32(kdec0, kdec1, (uint32_t)(b - 32), (uint32_t)b, y0, y1); bits = y1; }
        const float u_dec = bits_to_u01(bits);
        const bool dp = (k > 1) && (u_dec < ((k >= 2) ? 0.5f : 0.0f));

        const int j = (b << 4) + t;
        uint32_t pb;
        if (j < 512) { tf2x32(kperm0, kperm1, (uint32_t)j, (uint32_t)(j + 512), y0, y1); pb = y0; }
        else         { tf2x32(kperm0, kperm1, (uint32_t)(j - 512), (uint32_t)j, y0, y1); pb = y1; }
        const float up = bits_to_u01(pb);

        const float INF = __int_as_float(0x7F800000);
        const float keyt = (t < k) ? up : INF;
        int r = 0;
#pragma unroll
        for (int tt = 0; tt < KMAX; ++tt) {
            float kt = __shfl(keyt, tt, 64);
            r += (kt < keyt) || (kt == keyt && tt < t);
        }

        if (s >= k)  { if (t == 0) { s_src = s; s_itau = 0.f; } }    // inactive: self-copy
        else if (dp) { if (r == s) { s_src = t; s_itau = 0.f; } }    // permuted: inverse perm
        else if (t == 0) {                                            // warp: tau for (b,s)
            const int js = (b << 4) + s;
            uint32_t tb;
            if (js < 512) { tf2x32(ktau0, ktau1, (uint32_t)js, (uint32_t)(js + 512), y0, y1); tb = y0; }
            else          { tf2x32(ktau0, ktau1, (uint32_t)(js - 512), (uint32_t)js, y0, y1); tb = y1; }
            const float tau = fmaxf(0.7f, bits_to_u01(tb) * 0.9f + 0.7f);
            s_src = -1; s_itau = 1.0f / tau;
        }
    }
    __syncthreads();

    const int src = s_src;
    const bool warp = (src < 0);
    const float it = s_itau;
    const float* sp = p_z + (size_t)((b << 4) + (warp ? s : src)) * VV;

    // ---- pass 1: aligned global loads -> LDS (pow applied for warp rows) ----
    float lsum = 0.f;
#pragma unroll
    for (int i = 0; i < 8; ++i) {
        const int q = tid + (i << 10);
        if (q < NQ) {
            float4 v = *(const float4*)(sp + (q << 2));
            if (warp) {
                v.x = exp2f(__log2f(fmaxf(v.x, EPSF)) * it);
                v.y = exp2f(__log2f(fmaxf(v.y, EPSF)) * it);
                v.z = exp2f(__log2f(fmaxf(v.z, EPSF)) * it);
                v.w = exp2f(__log2f(fmaxf(v.w, EPSF)) * it);
                lsum += v.x + v.y + v.z + v.w;
            }
            *(float4*)&buf[q << 2] = v;
        }
    }

    float scale = 1.0f;
    if (warp) {
        float t = lsum;
#pragma unroll
        for (int o = 32; o; o >>= 1) t += __shfl_down(t, o, 64);
        if ((tid & 63) == 0) red1[tid >> 6] = t;
        __syncthreads();
        if (tid < 64) {
            float u = (tid < 16) ? red1[tid] : 0.0f;
#pragma unroll
            for (int o = 8; o; o >>= 1) u += __shfl_down(u, o, 64);
            if (tid == 0) red1[0] = u;
        }
        __syncthreads();
        scale = 1.0f / red1[0];
    } else {
        __syncthreads();
    }

    // ---- pass 2: LDS shifted read -> aligned NT stores ----
#pragma unroll
    for (int i = 0; i < 8; ++i) {
        const int q = tid + (i << 10);
        if (q < NQ - 1) {
            const int e = (q << 2) + 1;
            nt_store4(dst + e,
                      buf[e] * scale, buf[e + 1] * scale,
                      buf[e + 2] * scale, buf[e + 3] * scale);
        }
    }
    if (tid == 0) dst[0] = buf[0] * scale;
    if (tid == 1) {
        dst[VV - 3] = buf[VV - 3] * scale;
        dst[VV - 2] = buf[VV - 2] * scale;
        dst[VV - 1] = buf[VV - 1] * scale;
    }
}

// ------------- per-batch reductions over h_ans (H=4096) -------------
__global__ __launch_bounds__(256) void rowred_kernel(const float* __restrict__ hr,
                                                     const float* __restrict__ hc,
                                                     float* __restrict__ cosb,
                                                     float* __restrict__ depb) {
    int b = blockIdx.x;
    const float4* r4 = (const float4*)(hr + (size_t)b * HH);
    const float4* c4 = (const float4*)(hc + (size_t)b * HH);
    float srr = 0.f, scc = 0.f, sxc = 0.f, sdd = 0.f;
    for (int i = threadIdx.x; i < HH / 4; i += 256) {
        float4 r = r4[i], c = c4[i];
        srr += r.x * r.x + r.y * r.y + r.z * r.z + r.w * r.w;
        scc += c.x * c.x + c.y * c.y + c.z * c.z + c.w * c.w;
        sxc += r.x * c.x + r.y * c.y + r.z * c.z + r.w * c.w;
        float dx = r.x - c.x, dy = r.y - c.y, dz = r.z - c.z, dw = r.w - c.w;
        sdd += dx * dx + dy * dy + dz * dz + dw * dw;
    }
#pragma unroll
    for (int o = 32; o; o >>= 1) {
        srr += __shfl_down(srr, o, 64);
        scc += __shfl_down(scc, o, 64);
        sxc += __shfl_down(sxc, o, 64);
        sdd += __shfl_down(sdd, o, 64);
    }
    __shared__ float red[4][4];
    int w = threadIdx.x >> 6;
    if ((threadIdx.x & 63) == 0) { red[w][0] = srr; red[w][1] = scc; red[w][2] = sxc; red[w][3] = sdd; }
    __syncthreads();
    if (threadIdx.x == 0) {
        float t0 = 0.f, t1 = 0.f, t2 = 0.f, t3 = 0.f;
        for (int i = 0; i < 4; ++i) { t0 += red[i][0]; t1 += red[i][1]; t2 += red[i][2]; t3 += red[i][3]; }
        float nr = fmaxf(sqrtf(t0), 1e-12f);
        float nc = fmaxf(sqrtf(t1), 1e-12f);
        cosb[b] = t2 / (nr * nc);
        depb[b] = sqrtf(t3);
    }
}

// ------------- JS divergence + final scalars -------------
__global__ void finalize_kernel(const float* __restrict__ dlr, const float* __restrict__ dlc,
                                const float* __restrict__ cosb, const float* __restrict__ depb,
                                float* __restrict__ out) {
    int b = threadIdx.x;  // 64 threads = 1 wave
    float lr[DVV], lc[DVV];
    float mr = -1e30f, mc = -1e30f;
#pragma unroll
    for (int v = 0; v < DVV; ++v) {
        lr[v] = dlr[b * DVV + v]; lc[v] = dlc[b * DVV + v];
        mr = fmaxf(mr, lr[v]); mc = fmaxf(mc, lc[v]);
    }
    float sr = 0.f, sc = 0.f;
#pragma unroll
    for (int v = 0; v < DVV; ++v) {
        lr[v] = expf(lr[v] - mr); sr += lr[v];
        lc[v] = expf(lc[v] - mc); sc += lc[v];
    }
    float js = 0.f;
#pragma unroll
    for (int v = 0; v < DVV; ++v) {
        float p = fmaxf(lr[v] / sr, EPSF);
        float q = fmaxf(lc[v] / sc, EPSF);
        float m = 0.5f * (p + q);
        float lm = logf(m);
        js += 0.5f * (p * (logf(p) - lm) + q * (logf(q) - lm));
    }
    float cs = cosb[b], dp = depb[b];
#pragma unroll
    for (int o = 32; o; o >>= 1) {
        js += __shfl_down(js, o, 64);
        cs += __shfl_down(cs, o, 64);
        dp += __shfl_down(dp, o, 64);
    }
    if (b == 0) {
        out[0] = logf(2.0f) - js * (1.0f / 64.0f);
        out[1] = cs * (1.0f / 64.0f) - 1.0f;
        out[2] = dp * (1.0f / 64.0f);
    }
}

extern "C" void kernel_launch(void* const* d_in, const int* in_sizes, int n_in,
                              void* d_out, int out_size, void* d_ws, size_t ws_size,
                              hipStream_t stream) {
    const float* p_z = (const float*)d_in[0];
    const float* dlr = (const float*)d_in[1];
    const float* dlc = (const float*)d_in[2];
    const float* hr  = (const float*)d_in[3];
    const float* hc  = (const float*)d_in[4];
    const int*   kv  = (const int*)d_in[5];
    float* out = (float*)d_out;

    float* cosb = (float*)d_ws;
    float* depb = cosb + NB;

    cf_main_kernel<<<NROWS, 1024, 0, stream>>>(p_z, kv, out);
    rowred_kernel<<<NB, 256, 0, stream>>>(hr, hc, cosb, depb);
    finalize_kernel<<<1, 64, 0, stream>>>(dlr, dlc, cosb, depb, out);
}